// Round 1
// baseline (1520.167 us; speedup 1.0000x reference)
//
#include <hip/hip_runtime.h>
#include <math.h>

#define BB 512
#define TT 1024
#define LL 48
#define PF 8           // emission prefetch depth (loads in flight, per batch)

__device__ __forceinline__ float readlane_f(float v, int lane) {
    return __int_as_float(__builtin_amdgcn_readlane(__float_as_int(v), lane));
}

// Tournament argmax over s[0..47], first-max tie-break (epilogue only).
__device__ __forceinline__ void argmax48(const float* s, float& bestv, int& besti) {
    float val[24];
    int   idx[24];
#pragma unroll
    for (int k = 0; k < 24; ++k) {
        bool c = s[2 * k + 1] > s[2 * k];
        val[k] = c ? s[2 * k + 1] : s[2 * k];
        idx[k] = c ? 2 * k + 1 : 2 * k;
    }
#pragma unroll
    for (int k = 0; k < 12; ++k) {
        bool c = val[2 * k + 1] > val[2 * k];
        val[k] = c ? val[2 * k + 1] : val[2 * k];
        idx[k] = c ? idx[2 * k + 1] : idx[2 * k];
    }
#pragma unroll
    for (int k = 0; k < 6; ++k) {
        bool c = val[2 * k + 1] > val[2 * k];
        val[k] = c ? val[2 * k + 1] : val[2 * k];
        idx[k] = c ? idx[2 * k + 1] : idx[2 * k];
    }
#pragma unroll
    for (int k = 0; k < 3; ++k) {
        bool c = val[2 * k + 1] > val[2 * k];
        val[k] = c ? val[2 * k + 1] : val[2 * k];
        idx[k] = c ? idx[2 * k + 1] : idx[2 * k];
    }
    bool c01 = val[1] > val[0];
    float bv = c01 ? val[1] : val[0];
    int   bi = c01 ? idx[1] : idx[0];
    bool c2 = val[2] > bv;
    bestv = c2 ? val[2] : bv;
    besti = c2 ? idx[2] : bi;
}

// One wave handles TWO batch elements (independent Viterbi chains) so the
// ~60% dependency-stall bubbles of one chain are filled by the other.
__global__ __launch_bounds__(64, 1) void viterbi_kernel(
    const float* __restrict__ emissions,   // [B,T,L]
    const float* __restrict__ transitions, // [L,L]
    const float* __restrict__ start_tr,    // [L]
    const float* __restrict__ end_tr,      // [L]
    int* __restrict__ out)                 // [B,T] int32
{
    extern __shared__ unsigned char bp[];  // 2 * (TT-1)*LL = 98,208 B
    unsigned char* bpA = bp;
    unsigned char* bpB = bp + (TT - 1) * LL;

    const int bA = blockIdx.x * 2;
    const int bB = bA + 1;
    const int j  = threadIdx.x;
    const int jc = (j < LL) ? j : (LL - 1);       // lanes 48-63 mirror lane 47

    // Transition column jc in registers: tc[i] = transitions[i][jc] (shared A/B)
    float tc[LL];
#pragma unroll
    for (int i = 0; i < LL; ++i)
        tc[i] = transitions[i * LL + jc];

    const float* emA = emissions + (size_t)bA * TT * LL;
    const float* emB = emissions + (size_t)bB * TT * LL;

    float vA = start_tr[jc] + emA[jc];
    float vB = start_tr[jc] + emB[jc];

    // 8-deep emission prefetch rings, one per batch.
    float erA[PF], erB[PF];
#pragma unroll
    for (int k = 0; k < PF; ++k) {
        erA[k] = emA[(size_t)(1 + k) * LL + jc];
        erB[k] = emB[(size_t)(1 + k) * LL + jc];
    }

    // One Viterbi step for both batches, statement-interleaved for ILP.
    auto step2 = [&](int t, float eA, float eB) {
        float sA[LL], sB[LL];
#pragma unroll
        for (int i = 0; i < LL; ++i) {
            sA[i] = readlane_f(vA, i) + tc[i];
            sB[i] = readlane_f(vB, i) + tc[i];
        }

        // value-only max3 trees (depth 4), interleaved
        float m1A[16], m1B[16];
#pragma unroll
        for (int k = 0; k < 16; ++k) {
            m1A[k] = fmaxf(fmaxf(sA[3 * k], sA[3 * k + 1]), sA[3 * k + 2]);
            m1B[k] = fmaxf(fmaxf(sB[3 * k], sB[3 * k + 1]), sB[3 * k + 2]);
        }
        float m2A[6], m2B[6];
#pragma unroll
        for (int k = 0; k < 5; ++k) {
            m2A[k] = fmaxf(fmaxf(m1A[3 * k], m1A[3 * k + 1]), m1A[3 * k + 2]);
            m2B[k] = fmaxf(fmaxf(m1B[3 * k], m1B[3 * k + 1]), m1B[3 * k + 2]);
        }
        m2A[5] = m1A[15];
        m2B[5] = m1B[15];
        float bestA = fmaxf(fmaxf(fmaxf(m2A[0], m2A[1]), m2A[2]),
                            fmaxf(fmaxf(m2A[3], m2A[4]), m2A[5]));
        float bestB = fmaxf(fmaxf(fmaxf(m2B[0], m2B[1]), m2B[2]),
                            fmaxf(fmaxf(m2B[3], m2B[4]), m2B[5]));

        vA = bestA + eA;                          // serial chains continue here
        vB = bestB + eB;

        // off-chain: first i with s[i]==best (exact: best is bitwise one of s)
        int a0 = 63, a1 = 63, a2 = 63, a3 = 63;
        int b0 = 63, b1 = 63, b2 = 63, b3 = 63;
#pragma unroll
        for (int k = 11; k >= 0; --k) {           // descending => lowest k wins
            if (sA[k]      == bestA) a0 = k;
            if (sA[12 + k] == bestA) a1 = 12 + k;
            if (sA[24 + k] == bestA) a2 = 24 + k;
            if (sA[36 + k] == bestA) a3 = 36 + k;
            if (sB[k]      == bestB) b0 = k;
            if (sB[12 + k] == bestB) b1 = 12 + k;
            if (sB[24 + k] == bestB) b2 = 24 + k;
            if (sB[36 + k] == bestB) b3 = 36 + k;
        }
        int argA = min(min(a0, a1), min(a2, a3)); // first-max tie-break
        int argB = min(min(b0, b1), min(b2, b3));

        bpA[(t - 1) * LL + jc] = (unsigned char)argA;
        bpB[(t - 1) * LL + jc] = (unsigned char)argB;
    };

    // Main loop: blocks of 8 with compile-time-constant ring indices.
    int tb = 1;
    for (; tb + PF <= TT; tb += PF) {
#pragma unroll
        for (int k = 0; k < PF; ++k) {
            int t = tb + k;
            float eA = erA[k];
            float eB = erB[k];
            int tn = t + PF; if (tn > TT - 1) tn = TT - 1;   // scalar clamp
            erA[k] = emA[(size_t)tn * LL + jc];   // refills: loads in flight
            erB[k] = emB[(size_t)tn * LL + jc];
            step2(t, eA, eB);
        }
    }
    // Tail: remaining steps, emissions already resident in the rings.
#pragma unroll
    for (int k = 0; k < PF - 1; ++k) {
        int t = tb + k;
        if (t < TT) step2(t, erA[k], erB[k]);
    }

    // ---- epilogue: final tags (tournament keeps exact tie-break) ----
    vA += end_tr[jc];
    vB += end_tr[jc];
    float sfA[LL], sfB[LL];
#pragma unroll
    for (int i = 0; i < LL; ++i) {
        sfA[i] = readlane_f(vA, i);
        sfB[i] = readlane_f(vB, i);
    }
    float bvA, bvB; int tagA, tagB;
    argmax48(sfA, bvA, tagA);                     // wave-uniform
    argmax48(sfB, bvB, tagB);

    int* obA = out + (size_t)bA * TT;
    int* obB = out + (size_t)bB * TT;
    if (j == 0) {
        obA[TT - 1] = tagA;
        obB[TT - 1] = tagB;
    }

    // ---- backtrack: coalesced row loads + readlane chains, both batches ----
    for (int hi = TT - 2; hi >= 0; hi -= 32) {
        int lo = hi - 31; if (lo < 0) lo = 0;
        int n = hi - lo + 1;

        unsigned int rowA[32], rowB[32];
#pragma unroll
        for (int k = 0; k < 32; ++k) {
            rowA[k] = (unsigned int)bpA[(lo + k) * LL + jc];
            rowB[k] = (unsigned int)bpB[(lo + k) * LL + jc];
        }

        int outA = 0, outB = 0;
#pragma unroll
        for (int k = 31; k >= 0; --k) {
            if (k < n) {
                tagA = __builtin_amdgcn_readlane((int)rowA[k], tagA);
                outA = (j == k) ? tagA : outA;    // tag is SGPR -> one cndmask
                tagB = __builtin_amdgcn_readlane((int)rowB[k], tagB);
                outB = (j == k) ? tagB : outB;
            }
        }
        if (j < n) {
            obA[lo + j] = outA;
            obB[lo + j] = outB;
        }
    }
}

extern "C" void kernel_launch(void* const* d_in, const int* in_sizes, int n_in,
                              void* d_out, int out_size, void* d_ws, size_t ws_size,
                              hipStream_t stream) {
    const float* emissions   = (const float*)d_in[0];
    // d_in[1] = mask — unused by the reference decode body
    const float* transitions = (const float*)d_in[2];
    const float* start_tr    = (const float*)d_in[3];
    const float* end_tr      = (const float*)d_in[4];
    int* out = (int*)d_out;

    const int lds_bytes = 2 * (TT - 1) * LL;      // 98,208 B (< 160 KiB/CU)

    static bool attr_set = false;
    if (!attr_set) {
        // Opt-in for >64 KiB dynamic LDS (no-op / harmless if unsupported).
        (void)hipFuncSetAttribute((const void*)viterbi_kernel,
                                  hipFuncAttributeMaxDynamicSharedMemorySize,
                                  lds_bytes);
        attr_set = true;
    }

    viterbi_kernel<<<dim3(BB / 2), dim3(64), lds_bytes, stream>>>(
        emissions, transitions, start_tr, end_tr, out);
}